// Round 5
// baseline (1405.025 us; speedup 1.0000x reference)
//
#include <hip/hip_runtime.h>
#include <hip/hip_bf16.h>
#include <hip/hip_fp16.h>

#define D 512

typedef _Float16 half8 __attribute__((ext_vector_type(8)));
typedef _Float16 half4v __attribute__((ext_vector_type(4)));
typedef float floatx4 __attribute__((ext_vector_type(4)));

// ---------------- conversion kernels ----------------

__global__ void k_f32_to_f16(const float* __restrict__ in, _Float16* __restrict__ out, int n4) {
  int i = blockIdx.x * blockDim.x + threadIdx.x;
  if (i >= n4) return;
  floatx4 v = __builtin_nontemporal_load((const floatx4*)in + i);
  half4v h;
  h[0] = (_Float16)v[0]; h[1] = (_Float16)v[1]; h[2] = (_Float16)v[2]; h[3] = (_Float16)v[3];
  ((half4v*)out)[i] = h;  // xh reused by agg + GEMM -> cacheable
}

// wT[jg][k] = w_m[k][j],  jg = m*512 + j  (B^T layout for MFMA)
__global__ void k_build_wt(const float* __restrict__ w1, const float* __restrict__ w2,
                           const float* __restrict__ w3, _Float16* __restrict__ wT) {
  int id = blockIdx.x * blockDim.x + threadIdx.x;
  if (id >= 3 * D * D) return;
  int jg = id >> 9;
  int k  = id & (D - 1);
  const float* w = (jg < D) ? w1 : (jg < 2 * D ? w2 : w3);
  int j = jg & (D - 1);
  wT[id] = (_Float16)w[k * D + j];
}

// ---------------- CSR build ----------------

__global__ void k_count(const int* __restrict__ row, int* __restrict__ counts, int E) {
  int i = blockIdx.x * blockDim.x + threadIdx.x;
  if (i < E) atomicAdd(&counts[row[i]], 1);
}

__global__ __launch_bounds__(256) void k_scan1(const int* __restrict__ in, int* __restrict__ out,
                                               int* __restrict__ bsums, int n) {
  __shared__ int wsum[4];
  int t = threadIdx.x, lane = t & 63, wd = t >> 6;
  int i0 = blockIdx.x * 1024 + t * 4;
  int4 c = make_int4(0, 0, 0, 0);
  if (i0 + 3 < n) c = *(const int4*)(in + i0);
  else {
    if (i0 < n) c.x = in[i0];
    if (i0 + 1 < n) c.y = in[i0 + 1];
    if (i0 + 2 < n) c.z = in[i0 + 2];
  }
  int s1 = c.x, s2 = s1 + c.y, s3 = s2 + c.z, s4 = s3 + c.w;
  int x = s4;
#pragma unroll
  for (int o = 1; o < 64; o <<= 1) { int p = __shfl_up(x, o); if (lane >= o) x += p; }
  if (lane == 63) wsum[wd] = x;
  __syncthreads();
  int wex = 0;
  for (int k = 0; k < wd; ++k) wex += wsum[k];
  int base = wex + x - s4;
  if (i0 + 3 < n) *(int4*)(out + i0) = make_int4(base, base + s1, base + s2, base + s3);
  else {
    if (i0 < n) out[i0] = base;
    if (i0 + 1 < n) out[i0 + 1] = base + s1;
    if (i0 + 2 < n) out[i0 + 2] = base + s2;
  }
  if (t == 0) bsums[blockIdx.x] = wsum[0] + wsum[1] + wsum[2] + wsum[3];
}

__global__ void k_scan2(int* __restrict__ bsums, int* __restrict__ total_out, int nb) {
  __shared__ int w0;
  int t = threadIdx.x, lane = t & 63, wd = t >> 6;
  int v = (t < nb) ? bsums[t] : 0;
  int x = v;
#pragma unroll
  for (int o = 1; o < 64; o <<= 1) { int p = __shfl_up(x, o); if (lane >= o) x += p; }
  if (wd == 0 && lane == 63) w0 = x;
  __syncthreads();
  int excl = x - v + (wd ? w0 : 0);
  if (t < nb) bsums[t] = excl;
  if (t == 127) *total_out = w0 + x;
}

__global__ __launch_bounds__(256) void k_scan3(int* __restrict__ out, const int* __restrict__ bsums, int n) {
  int t = threadIdx.x;
  int i0 = blockIdx.x * 1024 + t * 4;
  int add = bsums[blockIdx.x];
  if (i0 + 3 < n) {
    int4 v = *(int4*)(out + i0);
    v.x += add; v.y += add; v.z += add; v.w += add;
    *(int4*)(out + i0) = v;
  } else {
    for (int k = 0; k < 4; ++k) if (i0 + k < n) out[i0 + k] += add;
  }
}

__global__ void k_scatter(const int* __restrict__ row, const int* __restrict__ col,
                          const float* __restrict__ val, const int* __restrict__ offsets,
                          int* __restrict__ cursor, long long* __restrict__ edges, int E) {
  int i = blockIdx.x * blockDim.x + threadIdx.x;
  if (i >= E) return;
  int r = row[i];
  int c = __builtin_nontemporal_load(col + i);
  float v = __builtin_nontemporal_load(val + i);
  int p = offsets[r] + atomicAdd(&cursor[r], 1);
  long long pack = ((long long)(unsigned)__float_as_int(v) << 32) | (unsigned)c;
  __builtin_nontemporal_store(pack, edges + p);
}

// ---------------- sparse aggregation on xh:  y = A_sp @ xh  (f16 out) --------
// CHANNEL-SPLIT: two waves per node, each owning 256 channels (8B/lane gather).
// Grid halves run in dispatch order: first ~half of the kernel sweeps only the
// low 256 channels (51MB footprint), then the high 256 -> the synchronized
// col-sweep window holds 2x more nodes in L2 -> higher gather hit rate.
// Per 64-edge chunk: bitonic-sort by col (keeps all waves sweeping cols
// monotonically in phase), shfl-broadcast, 8-deep gather.
__global__ __launch_bounds__(256) void k_agg(
    const _Float16* __restrict__ xh, _Float16* __restrict__ yh,
    const int* __restrict__ offsets, const long long* __restrict__ edges, int n)
{
  int gwid = (blockIdx.x * 256 + threadIdx.x) >> 6;
  if (gwid >= 2 * n) return;
  int half = (gwid >= n) ? 1 : 0;
  int wid = half ? (gwid - n) : gwid;
  int lane = threadIdx.x & 63;
  int s = offsets[wid], e = offsets[wid + 1];
  float acc[4] = {0, 0, 0, 0};
  const half4v* x4 = (const half4v*)xh;
  int cidx = half * 64 + lane;   // half4v index within a 128-unit row

  for (int base = s; base < e; base += 64) {
    int cnt = e - base; if (cnt > 64) cnt = 64;
    int key = 0x7fffffff; float val = 0.f;
    if (lane < cnt) {
      long long ed = __builtin_nontemporal_load(edges + base + lane);
      key = (int)(unsigned)(ed & 0xffffffffll);
      val = __int_as_float((int)(ed >> 32));
    }
    // 64-lane bitonic sort (key=col, payload=val)
#pragma unroll
    for (int size = 2; size <= 64; size <<= 1) {
#pragma unroll
      for (int stride = size >> 1; stride; stride >>= 1) {
        int pk = __shfl_xor(key, stride);
        float pv = __shfl_xor(val, stride);
        bool upper = (lane & stride) != 0;
        bool desc = (lane & size) != 0;
        bool takemax = upper != desc;
        bool swap = takemax ? (pk > key) : (pk < key);
        if (swap) { key = pk; val = pv; }
      }
    }
    int i = 0;
    for (; i + 8 <= cnt; i += 8) {
      int cc[8]; float vv[8];
#pragma unroll
      for (int u = 0; u < 8; ++u) { cc[u] = __shfl(key, i + u); vv[u] = __shfl(val, i + u); }
      half4v h[8];
#pragma unroll
      for (int u = 0; u < 8; ++u) h[u] = x4[(size_t)cc[u] * 128 + cidx];
#pragma unroll
      for (int j = 0; j < 4; ++j) {
        float a = acc[j];
#pragma unroll
        for (int u = 0; u < 8; ++u) a += vv[u] * (float)h[u][j];
        acc[j] = a;
      }
    }
    for (; i + 4 <= cnt; i += 4) {
      int c0 = __shfl(key, i),     c1 = __shfl(key, i + 1);
      int c2 = __shfl(key, i + 2), c3 = __shfl(key, i + 3);
      float v0 = __shfl(val, i),     v1 = __shfl(val, i + 1);
      float v2 = __shfl(val, i + 2), v3 = __shfl(val, i + 3);
      half4v h0 = x4[(size_t)c0 * 128 + cidx];
      half4v h1 = x4[(size_t)c1 * 128 + cidx];
      half4v h2 = x4[(size_t)c2 * 128 + cidx];
      half4v h3 = x4[(size_t)c3 * 128 + cidx];
#pragma unroll
      for (int j = 0; j < 4; ++j)
        acc[j] += v0 * (float)h0[j] + v1 * (float)h1[j] + v2 * (float)h2[j] + v3 * (float)h3[j];
    }
    for (; i < cnt; ++i) {
      int c0 = __shfl(key, i);
      float v0 = __shfl(val, i);
      half4v h0 = x4[(size_t)c0 * 128 + cidx];
#pragma unroll
      for (int j = 0; j < 4; ++j) acc[j] += v0 * (float)h0[j];
    }
  }

  half4v o;
#pragma unroll
  for (int j = 0; j < 4; ++j) o[j] = (_Float16)acc[j];
  ((half4v*)yh)[(size_t)wid * 128 + cidx] = o;  // read by GEMM -> cacheable
}

// ---------------- fully fused triple GEMM + epilogue -------------------------
// Block computes, for 128 rows x 64 cols: agg = y@w1, trans = x@w2, gate =
// sigmoid(x@w3); epilogue fused, single NT store of out.
// XCD-aware bijective swizzle (T1/m204) + T3-minimal 2-phase pipeline:
// double-buffered LDS, STAGE(k+1) issued BEFORE compute(k), one barrier/step
// -> DMA latency hides under ds_read+MFMA of the current step.
__global__ __launch_bounds__(256) void k_gemm_fused(
    const _Float16* __restrict__ Ax,  // xh [M][512]
    const _Float16* __restrict__ Ay,  // yh [M][512]
    const _Float16* __restrict__ BT,  // wT [1536][512], row jg = m*512 + j
    const float* __restrict__ b1, const float* __restrict__ b2,
    const float* __restrict__ b3, float* __restrict__ out, int M)
{
  __shared__ __align__(16) _Float16 ldsAx[2][128 * 32];
  __shared__ __align__(16) _Float16 ldsAy[2][128 * 32];
  __shared__ __align__(16) _Float16 ldsB[2][192 * 32];
  int t = threadIdx.x;
  int nrb = (M + 127) >> 7;
  int bid = blockIdx.x;
  int wq = (bid & 7) * nrb + (bid >> 3);   // bijection since gridDim.x = 8*nrb
  int rowBase = (wq >> 3) << 7;
  int cb = wq & 7;                          // col block: cols [cb*64, cb*64+64)
  int w = t >> 6, lane = t & 63, lr = lane & 15, quad = lane >> 4;
  floatx4 acc[3][2][4] = {};                // [mat][rowfrag][colfrag]

  int srow0 = lane >> 2;
  int schunk = lane & 3;

  auto stage = [&](int buf, int k0) {
    // A (xh + yh): wave w stages rows [w*32, w*32+32)
#pragma unroll
    for (int c = 0; c < 2; ++c) {
      int srow = w * 32 + c * 16 + srow0;
      int chunk = schunk ^ ((srow >> 1) & 3);
      int ga = rowBase + srow; if (ga >= M) ga = M - 1;
      const _Float16* gx = Ax + (size_t)ga * D + k0 + chunk * 8;
      const _Float16* gy = Ay + (size_t)ga * D + k0 + chunk * 8;
      _Float16* lx = &ldsAx[buf][(w * 32 + c * 16) * 32];
      _Float16* ly = &ldsAy[buf][(w * 32 + c * 16) * 32];
      __builtin_amdgcn_global_load_lds((const __attribute__((address_space(1))) void*)gx,
                                       (__attribute__((address_space(3))) void*)lx, 16, 0, 0);
      __builtin_amdgcn_global_load_lds((const __attribute__((address_space(1))) void*)gy,
                                       (__attribute__((address_space(3))) void*)ly, 16, 0, 0);
    }
    // B: 192 rows (3 mats x 64 cols); wave w stages rows [w*48, w*48+48)
#pragma unroll
    for (int c = 0; c < 3; ++c) {
      int srow = w * 48 + c * 16 + srow0;          // 0..191
      int chunk = schunk ^ ((srow >> 1) & 3);
      int m = srow >> 6, j = srow & 63;
      const _Float16* gB = BT + (size_t)(m * 512 + cb * 64 + j) * D + k0 + chunk * 8;
      _Float16* lB = &ldsB[buf][(w * 48 + c * 16) * 32];
      __builtin_amdgcn_global_load_lds((const __attribute__((address_space(1))) void*)gB,
                                       (__attribute__((address_space(3))) void*)lB, 16, 0, 0);
    }
  };

  stage(0, 0);
  __syncthreads();   // compiler emits vmcnt(0) drain before barrier

  for (int kt = 0; kt < 16; ++kt) {
    int cur = kt & 1;
    if (kt < 15) stage(cur ^ 1, (kt + 1) * 32);   // prefetch next K-tile

    half8 afx[2], afy[2];
#pragma unroll
    for (int i2 = 0; i2 < 2; ++i2) {
      int r = w * 32 + i2 * 16 + lr;
      int sl = (quad ^ ((r >> 1) & 3)) << 3;
      afx[i2] = *(const half8*)&ldsAx[cur][r * 32 + sl];
      afy[i2] = *(const half8*)&ldsAy[cur][r * 32 + sl];
    }
#pragma unroll
    for (int m = 0; m < 3; ++m) {
      half8 bf[4];
#pragma unroll
      for (int f = 0; f < 4; ++f) {
        int r = m * 64 + f * 16 + lr;
        bf[f] = *(const half8*)&ldsB[cur][r * 32 + ((quad ^ ((r >> 1) & 3)) << 3)];
      }
#pragma unroll
      for (int i2 = 0; i2 < 2; ++i2)
#pragma unroll
        for (int f = 0; f < 4; ++f)
          acc[m][i2][f] = __builtin_amdgcn_mfma_f32_16x16x32_f16(
              m == 0 ? afy[i2] : afx[i2], bf[f], acc[m][i2][f], 0, 0, 0);
    }
    __syncthreads();   // drains next-tile DMA (vmcnt) + this tile's ds_reads
  }

  // epilogue: C/D layout col = lane&15, row = quad*4 + reg
#pragma unroll
  for (int i2 = 0; i2 < 2; ++i2) {
    int r0 = rowBase + w * 32 + i2 * 16 + quad * 4;
#pragma unroll
    for (int f = 0; f < 4; ++f) {
      int c = cb * 64 + f * 16 + lr;
      float bb1 = b1[c], bb2 = b2[c], bb3 = b3[c];
#pragma unroll
      for (int rg = 0; rg < 4; ++rg) {
        int r = r0 + rg;
        if (r >= M) continue;
        float aggv = acc[0][i2][f][rg] + bb1;
        aggv = aggv > 0.f ? aggv : 0.f;
        float tr = acc[1][i2][f][rg] + bb2;
        float gv = acc[2][i2][f][rg] + bb3;
        gv = 1.0f / (1.0f + __expf(-gv));
        __builtin_nontemporal_store(tr + gv * (aggv - tr), &out[(size_t)r * D + c]);
      }
    }
  }
}

// ---------------- launch ----------------

extern "C" void kernel_launch(void* const* d_in, const int* in_sizes, int n_in,
                              void* d_out, int out_size, void* d_ws, size_t ws_size,
                              hipStream_t stream) {
  const float* x    = (const float*)d_in[0];
  const float* w1   = (const float*)d_in[1];
  const float* w2   = (const float*)d_in[2];
  const float* w3   = (const float*)d_in[3];
  const float* b1   = (const float*)d_in[4];
  const float* b2   = (const float*)d_in[5];
  const float* b3   = (const float*)d_in[6];
  const int*   erow = (const int*)d_in[7];
  const int*   ecol = (const int*)d_in[8];
  const float* eval = (const float*)d_in[9];
  float* out = (float*)d_out;

  int N = in_sizes[0] / D;  // 100000
  int E = in_sizes[7];      // 3200000

  char* ws = (char*)d_ws;
  size_t off = 0;
  auto take = [&](size_t bytes) -> char* {
    char* p = ws + off;
    off += (bytes + 255) & ~(size_t)255;
    return p;
  };
  _Float16* xh    = (_Float16*)take((size_t)N * D * 2);
  _Float16* yh    = (_Float16*)take((size_t)N * D * 2);
  _Float16* wT    = (_Float16*)take((size_t)3 * D * D * 2);
  int* counts     = (int*)take((size_t)N * 4);
  int* cursor     = (int*)take((size_t)N * 4);
  int* offsets    = (int*)take((size_t)(N + 1) * 4);
  int* bsums      = (int*)take(128 * 4);
  long long* edges = (long long*)take((size_t)E * 8);

  hipMemsetAsync(counts, 0, (size_t)N * 4, stream);
  hipMemsetAsync(cursor, 0, (size_t)N * 4, stream);

  int n4 = N * D / 4;
  k_f32_to_f16<<<(n4 + 255) / 256, 256, 0, stream>>>(x, xh, n4);
  k_build_wt<<<(3 * D * D + 255) / 256, 256, 0, stream>>>(w1, w2, w3, wT);
  k_count<<<(E + 255) / 256, 256, 0, stream>>>(erow, counts, E);
  int nb = (N + 1023) / 1024;
  k_scan1<<<nb, 256, 0, stream>>>(counts, offsets, bsums, N);
  k_scan2<<<1, 128, 0, stream>>>(bsums, offsets + N, nb);
  k_scan3<<<nb, 256, 0, stream>>>(offsets, bsums, N);
  k_scatter<<<(E + 255) / 256, 256, 0, stream>>>(erow, ecol, eval, offsets, cursor, edges, E);
  k_agg<<<((size_t)2 * N * 64 + 255) / 256, 256, 0, stream>>>(xh, yh, offsets, edges, N);
  int nrb = (N + 127) / 128;
  k_gemm_fused<<<nrb * 8, 256, 0, stream>>>(xh, yh, wT, b1, b2, b3, out, N);
}

// Round 6
// 1238.586 us; speedup vs baseline: 1.1344x; 1.1344x over previous
//
#include <hip/hip_runtime.h>
#include <hip/hip_bf16.h>
#include <hip/hip_fp16.h>

#define D 512

typedef _Float16 half8 __attribute__((ext_vector_type(8)));
typedef _Float16 half4v __attribute__((ext_vector_type(4)));
typedef float floatx4 __attribute__((ext_vector_type(4)));

// ---------------- conversion kernels ----------------

__global__ void k_f32_to_f16(const float* __restrict__ in, _Float16* __restrict__ out, int n4) {
  int i = blockIdx.x * blockDim.x + threadIdx.x;
  if (i >= n4) return;
  floatx4 v = __builtin_nontemporal_load((const floatx4*)in + i);
  half4v h;
  h[0] = (_Float16)v[0]; h[1] = (_Float16)v[1]; h[2] = (_Float16)v[2]; h[3] = (_Float16)v[3];
  ((half4v*)out)[i] = h;  // xh reused by agg + GEMM -> cacheable
}

// wT[jg][k] = w_m[k][j],  jg = m*512 + j  (B^T layout for MFMA)
__global__ void k_build_wt(const float* __restrict__ w1, const float* __restrict__ w2,
                           const float* __restrict__ w3, _Float16* __restrict__ wT) {
  int id = blockIdx.x * blockDim.x + threadIdx.x;
  if (id >= 3 * D * D) return;
  int jg = id >> 9;
  int k  = id & (D - 1);
  const float* w = (jg < D) ? w1 : (jg < 2 * D ? w2 : w3);
  int j = jg & (D - 1);
  wT[id] = (_Float16)w[k * D + j];
}

// ---------------- CSR build ----------------
// k_count hands out slots via the atomic's return value -> no second atomic
// pass (cursor kernel eliminated; 3.2M fewer device-scope atomics).

__global__ void k_count(const int* __restrict__ row, int* __restrict__ counts,
                        int* __restrict__ slot, int E) {
  int i = blockIdx.x * blockDim.x + threadIdx.x;
  if (i < E) slot[i] = atomicAdd(&counts[row[i]], 1);
}

__global__ __launch_bounds__(256) void k_scan1(const int* __restrict__ in, int* __restrict__ out,
                                               int* __restrict__ bsums, int n) {
  __shared__ int wsum[4];
  int t = threadIdx.x, lane = t & 63, wd = t >> 6;
  int i0 = blockIdx.x * 1024 + t * 4;
  int4 c = make_int4(0, 0, 0, 0);
  if (i0 + 3 < n) c = *(const int4*)(in + i0);
  else {
    if (i0 < n) c.x = in[i0];
    if (i0 + 1 < n) c.y = in[i0 + 1];
    if (i0 + 2 < n) c.z = in[i0 + 2];
  }
  int s1 = c.x, s2 = s1 + c.y, s3 = s2 + c.z, s4 = s3 + c.w;
  int x = s4;
#pragma unroll
  for (int o = 1; o < 64; o <<= 1) { int p = __shfl_up(x, o); if (lane >= o) x += p; }
  if (lane == 63) wsum[wd] = x;
  __syncthreads();
  int wex = 0;
  for (int k = 0; k < wd; ++k) wex += wsum[k];
  int base = wex + x - s4;
  if (i0 + 3 < n) *(int4*)(out + i0) = make_int4(base, base + s1, base + s2, base + s3);
  else {
    if (i0 < n) out[i0] = base;
    if (i0 + 1 < n) out[i0 + 1] = base + s1;
    if (i0 + 2 < n) out[i0 + 2] = base + s2;
  }
  if (t == 0) bsums[blockIdx.x] = wsum[0] + wsum[1] + wsum[2] + wsum[3];
}

__global__ void k_scan2(int* __restrict__ bsums, int* __restrict__ total_out, int nb) {
  __shared__ int w0;
  int t = threadIdx.x, lane = t & 63, wd = t >> 6;
  int v = (t < nb) ? bsums[t] : 0;
  int x = v;
#pragma unroll
  for (int o = 1; o < 64; o <<= 1) { int p = __shfl_up(x, o); if (lane >= o) x += p; }
  if (wd == 0 && lane == 63) w0 = x;
  __syncthreads();
  int excl = x - v + (wd ? w0 : 0);
  if (t < nb) bsums[t] = excl;
  if (t == 127) *total_out = w0 + x;
}

__global__ __launch_bounds__(256) void k_scan3(int* __restrict__ out, const int* __restrict__ bsums, int n) {
  int t = threadIdx.x;
  int i0 = blockIdx.x * 1024 + t * 4;
  int add = bsums[blockIdx.x];
  if (i0 + 3 < n) {
    int4 v = *(int4*)(out + i0);
    v.x += add; v.y += add; v.z += add; v.w += add;
    *(int4*)(out + i0) = v;
  } else {
    for (int k = 0; k < 4; ++k) if (i0 + k < n) out[i0 + k] += add;
  }
}

// scatter: plain (cacheable) stores -- edges[] is 25.6MB <= 32MB aggregate L2,
// and one row's edges land in one 256B region, so L2 merges the random 8B
// stores into full-line writebacks (NT forced partial-line RMW at memory side).
__global__ void k_scatter(const int* __restrict__ row, const int* __restrict__ col,
                          const float* __restrict__ val, const int* __restrict__ offsets,
                          const int* __restrict__ slot, long long* __restrict__ edges, int E) {
  int i = blockIdx.x * blockDim.x + threadIdx.x;
  if (i >= E) return;
  int r = row[i];
  int c = __builtin_nontemporal_load(col + i);
  float v = __builtin_nontemporal_load(val + i);
  int p = offsets[r] + slot[i];
  long long pack = ((long long)(unsigned)__float_as_int(v) << 32) | (unsigned)c;
  edges[p] = pack;
}

// ---------------- sparse aggregation on xh:  y = A_sp @ xh  (f16 out) --------
// One wave per node; lane handles 8 channels (full 1KB row per gather);
// bitonic-sort 64-edge chunks by col; 16/8-deep gather batches.
// (R5 channel-split falsified the footprint-window model; this is the floor
// structure: ~436us, fabric-bound at ~7.3 TB/s L2-fill.)
__global__ __launch_bounds__(256) void k_agg(
    const _Float16* __restrict__ xh, _Float16* __restrict__ yh,
    const int* __restrict__ offsets, const long long* __restrict__ edges, int n)
{
  int wid = (blockIdx.x * 256 + threadIdx.x) >> 6;
  if (wid >= n) return;
  int lane = threadIdx.x & 63;
  int s = offsets[wid], e = offsets[wid + 1];
  float acc[8] = {0, 0, 0, 0, 0, 0, 0, 0};
  const half8* x8 = (const half8*)xh;

  for (int base = s; base < e; base += 64) {
    int cnt = e - base; if (cnt > 64) cnt = 64;
    int key = 0x7fffffff; float val = 0.f;
    if (lane < cnt) {
      long long ed = __builtin_nontemporal_load(edges + base + lane);
      key = (int)(unsigned)(ed & 0xffffffffll);
      val = __int_as_float((int)(ed >> 32));
    }
#pragma unroll
    for (int size = 2; size <= 64; size <<= 1) {
#pragma unroll
      for (int stride = size >> 1; stride; stride >>= 1) {
        int pk = __shfl_xor(key, stride);
        float pv = __shfl_xor(val, stride);
        bool upper = (lane & stride) != 0;
        bool desc = (lane & size) != 0;
        bool takemax = upper != desc;
        bool swap = takemax ? (pk > key) : (pk < key);
        if (swap) { key = pk; val = pv; }
      }
    }
    int i = 0;
    for (; i + 16 <= cnt; i += 16) {
      int cc[16]; float vv[16];
#pragma unroll
      for (int u = 0; u < 16; ++u) { cc[u] = __shfl(key, i + u); vv[u] = __shfl(val, i + u); }
      half8 h[16];
#pragma unroll
      for (int u = 0; u < 16; ++u) h[u] = x8[(size_t)cc[u] * 64 + lane];
#pragma unroll
      for (int j = 0; j < 8; ++j) {
        float a = acc[j];
#pragma unroll
        for (int u = 0; u < 16; ++u) a += vv[u] * (float)h[u][j];
        acc[j] = a;
      }
    }
    for (; i + 8 <= cnt; i += 8) {
      int cc[8]; float vv[8];
#pragma unroll
      for (int u = 0; u < 8; ++u) { cc[u] = __shfl(key, i + u); vv[u] = __shfl(val, i + u); }
      half8 h[8];
#pragma unroll
      for (int u = 0; u < 8; ++u) h[u] = x8[(size_t)cc[u] * 64 + lane];
#pragma unroll
      for (int j = 0; j < 8; ++j) {
        float a = acc[j];
#pragma unroll
        for (int u = 0; u < 8; ++u) a += vv[u] * (float)h[u][j];
        acc[j] = a;
      }
    }
    for (; i + 4 <= cnt; i += 4) {
      int c0 = __shfl(key, i),     c1 = __shfl(key, i + 1);
      int c2 = __shfl(key, i + 2), c3 = __shfl(key, i + 3);
      float v0 = __shfl(val, i),     v1 = __shfl(val, i + 1);
      float v2 = __shfl(val, i + 2), v3 = __shfl(val, i + 3);
      half8 h0 = x8[(size_t)c0 * 64 + lane];
      half8 h1 = x8[(size_t)c1 * 64 + lane];
      half8 h2 = x8[(size_t)c2 * 64 + lane];
      half8 h3 = x8[(size_t)c3 * 64 + lane];
#pragma unroll
      for (int j = 0; j < 8; ++j)
        acc[j] += v0 * (float)h0[j] + v1 * (float)h1[j] + v2 * (float)h2[j] + v3 * (float)h3[j];
    }
    for (; i < cnt; ++i) {
      int c0 = __shfl(key, i);
      float v0 = __shfl(val, i);
      half8 h0 = x8[(size_t)c0 * 64 + lane];
#pragma unroll
      for (int j = 0; j < 8; ++j) acc[j] += v0 * (float)h0[j];
    }
  }

  half8 o;
#pragma unroll
  for (int j = 0; j < 8; ++j) o[j] = (_Float16)acc[j];
  ((half8*)yh)[(size_t)wid * 64 + lane] = o;  // read by GEMM -> cacheable
}

// ---------------- fully fused triple GEMM + epilogue -------------------------
// Block computes, for 128 rows x 64 cols: agg = y@w1, trans = x@w2, gate =
// sigmoid(x@w3); epilogue fused, single NT store of out.
// XCD-aware bijective swizzle (T1/m204). SINGLE-buffered: 28KB LDS -> 5
// blocks/CU; implicit multi-block overlap (m114) hides staging latency.
// (R5 measured: explicit dbuf at 56KB -> 2 blocks/CU regressed ~65us.)
__global__ __launch_bounds__(256) void k_gemm_fused(
    const _Float16* __restrict__ Ax,  // xh [M][512]
    const _Float16* __restrict__ Ay,  // yh [M][512]
    const _Float16* __restrict__ BT,  // wT [1536][512], row jg = m*512 + j
    const float* __restrict__ b1, const float* __restrict__ b2,
    const float* __restrict__ b3, float* __restrict__ out, int M)
{
  __shared__ __align__(16) _Float16 ldsAx[128 * 32];
  __shared__ __align__(16) _Float16 ldsAy[128 * 32];
  __shared__ __align__(16) _Float16 ldsB[192 * 32];
  int t = threadIdx.x;
  int nrb = (M + 127) >> 7;
  int bid = blockIdx.x;
  int wq = (bid & 7) * nrb + (bid >> 3);   // bijection since gridDim.x = 8*nrb
  int rowBase = (wq >> 3) << 7;
  int cb = wq & 7;                          // col block: cols [cb*64, cb*64+64)
  int w = t >> 6, lane = t & 63, lr = lane & 15, quad = lane >> 4;
  floatx4 acc[3][2][4] = {};                // [mat][rowfrag][colfrag]

  int srow0 = lane >> 2;
  int schunk = lane & 3;

  for (int k0 = 0; k0 < D; k0 += 32) {
    // stage A (xh + yh): wave w stages rows [w*32, w*32+32)
#pragma unroll
    for (int c = 0; c < 2; ++c) {
      int srow = w * 32 + c * 16 + srow0;
      int chunk = schunk ^ ((srow >> 1) & 3);
      int ga = rowBase + srow; if (ga >= M) ga = M - 1;
      const _Float16* gx = Ax + (size_t)ga * D + k0 + chunk * 8;
      const _Float16* gy = Ay + (size_t)ga * D + k0 + chunk * 8;
      _Float16* lx = &ldsAx[(w * 32 + c * 16) * 32];
      _Float16* ly = &ldsAy[(w * 32 + c * 16) * 32];
      __builtin_amdgcn_global_load_lds((const __attribute__((address_space(1))) void*)gx,
                                       (__attribute__((address_space(3))) void*)lx, 16, 0, 0);
      __builtin_amdgcn_global_load_lds((const __attribute__((address_space(1))) void*)gy,
                                       (__attribute__((address_space(3))) void*)ly, 16, 0, 0);
    }
    // stage B: 192 rows (3 mats x 64 cols); wave w stages rows [w*48, w*48+48)
#pragma unroll
    for (int c = 0; c < 3; ++c) {
      int srow = w * 48 + c * 16 + srow0;          // 0..191
      int chunk = schunk ^ ((srow >> 1) & 3);
      int m = srow >> 6, j = srow & 63;
      const _Float16* gB = BT + (size_t)(m * 512 + cb * 64 + j) * D + k0 + chunk * 8;
      _Float16* lB = &ldsB[(w * 48 + c * 16) * 32];
      __builtin_amdgcn_global_load_lds((const __attribute__((address_space(1))) void*)gB,
                                       (__attribute__((address_space(3))) void*)lB, 16, 0, 0);
    }
    __syncthreads();

    half8 afx[2], afy[2];
#pragma unroll
    for (int i2 = 0; i2 < 2; ++i2) {
      int r = w * 32 + i2 * 16 + lr;
      int sl = (quad ^ ((r >> 1) & 3)) << 3;
      afx[i2] = *(const half8*)&ldsAx[r * 32 + sl];
      afy[i2] = *(const half8*)&ldsAy[r * 32 + sl];
    }
#pragma unroll
    for (int m = 0; m < 3; ++m) {
      half8 bf[4];
#pragma unroll
      for (int f = 0; f < 4; ++f) {
        int r = m * 64 + f * 16 + lr;
        bf[f] = *(const half8*)&ldsB[r * 32 + ((quad ^ ((r >> 1) & 3)) << 3)];
      }
#pragma unroll
      for (int i2 = 0; i2 < 2; ++i2)
#pragma unroll
        for (int f = 0; f < 4; ++f)
          acc[m][i2][f] = __builtin_amdgcn_mfma_f32_16x16x32_f16(
              m == 0 ? afy[i2] : afx[i2], bf[f], acc[m][i2][f], 0, 0, 0);
    }
    __syncthreads();
  }

  // epilogue: C/D layout col = lane&15, row = quad*4 + reg
#pragma unroll
  for (int i2 = 0; i2 < 2; ++i2) {
    int r0 = rowBase + w * 32 + i2 * 16 + quad * 4;
#pragma unroll
    for (int f = 0; f < 4; ++f) {
      int c = cb * 64 + f * 16 + lr;
      float bb1 = b1[c], bb2 = b2[c], bb3 = b3[c];
#pragma unroll
      for (int rg = 0; rg < 4; ++rg) {
        int r = r0 + rg;
        if (r >= M) continue;
        float aggv = acc[0][i2][f][rg] + bb1;
        aggv = aggv > 0.f ? aggv : 0.f;
        float tr = acc[1][i2][f][rg] + bb2;
        float gv = acc[2][i2][f][rg] + bb3;
        gv = 1.0f / (1.0f + __expf(-gv));
        __builtin_nontemporal_store(tr + gv * (aggv - tr), &out[(size_t)r * D + c]);
      }
    }
  }
}

// ---------------- launch ----------------

extern "C" void kernel_launch(void* const* d_in, const int* in_sizes, int n_in,
                              void* d_out, int out_size, void* d_ws, size_t ws_size,
                              hipStream_t stream) {
  const float* x    = (const float*)d_in[0];
  const float* w1   = (const float*)d_in[1];
  const float* w2   = (const float*)d_in[2];
  const float* w3   = (const float*)d_in[3];
  const float* b1   = (const float*)d_in[4];
  const float* b2   = (const float*)d_in[5];
  const float* b3   = (const float*)d_in[6];
  const int*   erow = (const int*)d_in[7];
  const int*   ecol = (const int*)d_in[8];
  const float* eval = (const float*)d_in[9];
  float* out = (float*)d_out;

  int N = in_sizes[0] / D;  // 100000
  int E = in_sizes[7];      // 3200000

  char* ws = (char*)d_ws;
  size_t off = 0;
  auto take = [&](size_t bytes) -> char* {
    char* p = ws + off;
    off += (bytes + 255) & ~(size_t)255;
    return p;
  };
  _Float16* xh    = (_Float16*)take((size_t)N * D * 2);
  _Float16* yh    = (_Float16*)take((size_t)N * D * 2);
  _Float16* wT    = (_Float16*)take((size_t)3 * D * D * 2);
  int* counts     = (int*)take((size_t)N * 4);
  int* offsets    = (int*)take((size_t)(N + 1) * 4);
  int* bsums      = (int*)take(128 * 4);
  int* slot       = (int*)take((size_t)E * 4);
  long long* edges = (long long*)take((size_t)E * 8);

  hipMemsetAsync(counts, 0, (size_t)N * 4, stream);

  int n4 = N * D / 4;
  k_f32_to_f16<<<(n4 + 255) / 256, 256, 0, stream>>>(x, xh, n4);
  k_build_wt<<<(3 * D * D + 255) / 256, 256, 0, stream>>>(w1, w2, w3, wT);
  k_count<<<(E + 255) / 256, 256, 0, stream>>>(erow, counts, slot, E);
  int nb = (N + 1023) / 1024;
  k_scan1<<<nb, 256, 0, stream>>>(counts, offsets, bsums, N);
  k_scan2<<<1, 128, 0, stream>>>(bsums, offsets + N, nb);
  k_scan3<<<nb, 256, 0, stream>>>(offsets, bsums, N);
  k_scatter<<<(E + 255) / 256, 256, 0, stream>>>(erow, ecol, eval, offsets, slot, edges, E);
  k_agg<<<((size_t)N * 64 + 255) / 256, 256, 0, stream>>>(xh, yh, offsets, edges, N);
  int nrb = (N + 127) / 128;
  k_gemm_fused<<<nrb * 8, 256, 0, stream>>>(xh, yh, wT, b1, b2, b3, out, N);
}